// Round 12
// baseline (1572.010 us; speedup 1.0000x reference)
//
#include <hip/hip_runtime.h>
#include <hip/hip_bf16.h>
#include <math.h>

#define S_ 2048
#define DM_ 2048
#define NPH (S_ / 2)

// Full-wave (64-lane) sum via DPP row_shr/row_bcast, broadcast via readlane.
__device__ __forceinline__ float wave_reduce_add_f32(float x) {
  float t;
  t = __int_as_float(__builtin_amdgcn_update_dpp(0, __float_as_int(x), 0x111, 0xf, 0xf, true)); x += t;
  t = __int_as_float(__builtin_amdgcn_update_dpp(0, __float_as_int(x), 0x112, 0xf, 0xf, true)); x += t;
  t = __int_as_float(__builtin_amdgcn_update_dpp(0, __float_as_int(x), 0x114, 0xf, 0xf, true)); x += t;
  t = __int_as_float(__builtin_amdgcn_update_dpp(0, __float_as_int(x), 0x118, 0xf, 0xf, true)); x += t;
  t = __int_as_float(__builtin_amdgcn_update_dpp(0, __float_as_int(x), 0x142, 0xa, 0xf, true)); x += t;
  t = __int_as_float(__builtin_amdgcn_update_dpp(0, __float_as_int(x), 0x143, 0xc, 0xf, true)); x += t;
  return __int_as_float(__builtin_amdgcn_readlane(__float_as_int(x), 63));
}

// ---------------------------------------------------------------------------
// K1: fused projections. proj row (stride 256): k(l2)@0 | v@64 | q(l2)@128 |
// a@192. (unchanged, harness-proven)
// ---------------------------------------------------------------------------
__global__ __launch_bounds__(256) void k_proj(
    const float* __restrict__ x, const float* __restrict__ Wk,
    const float* __restrict__ Wv, const float* __restrict__ Wq,
    const float* __restrict__ Wa, const float* __restrict__ Wab,
    const float* __restrict__ lam, float* __restrict__ proj,
    float* __restrict__ qwArr)
{
  __shared__ __align__(16) float xs[16 * 40];
  __shared__ __align__(16) float ws[32 * 260];
  const int tid = threadIdx.x;
  const int r0  = blockIdx.x * 16;
  const int ct  = tid & 63;
  const int rt  = tid >> 6;
  float acc[4][4];
  #pragma unroll
  for (int r = 0; r < 4; r++) { acc[r][0] = 0.f; acc[r][1] = 0.f; acc[r][2] = 0.f; acc[r][3] = 0.f; }

  const int sg = tid >> 3;
  const int sm = tid & 7;
  const float* wbase[4] = {Wk, Wv, Wq, Wa};

  for (int k0 = 0; k0 < DM_; k0 += 32) {
    if (tid < 128) {
      const int rr = tid >> 3;
      const int ko = (tid & 7) << 2;
      float4 xv = *(const float4*)(x + (size_t)(r0 + rr) * DM_ + k0 + ko);
      *(float4*)(xs + rr * 40 + ko) = xv;
    }
    #pragma unroll
    for (int p = 0; p < 8; p++) {
      const int c = sg + p * 32;
      const float* wb = wbase[p >> 1];
      const int cc = c - (p >> 1) * 64;
      float4 wv = *(const float4*)(wb + (size_t)cc * DM_ + k0 + sm * 4);
      ws[(sm * 4 + 0) * 260 + c] = wv.x;
      ws[(sm * 4 + 1) * 260 + c] = wv.y;
      ws[(sm * 4 + 2) * 260 + c] = wv.z;
      ws[(sm * 4 + 3) * 260 + c] = wv.w;
    }
    __syncthreads();
    #pragma unroll
    for (int kq = 0; kq < 8; kq++) {
      float4 xv[4];
      #pragma unroll
      for (int r = 0; r < 4; r++) xv[r] = *(const float4*)(xs + (rt * 4 + r) * 40 + kq * 4);
      #pragma unroll
      for (int i = 0; i < 4; i++) {
        const int kk = kq * 4 + i;
        float wv0 = ws[kk * 260 + ct];
        float wv1 = ws[kk * 260 + ct + 64];
        float wv2 = ws[kk * 260 + ct + 128];
        float wv3 = ws[kk * 260 + ct + 192];
        #pragma unroll
        for (int r = 0; r < 4; r++) {
          float xr = (i == 0) ? xv[r].x : (i == 1) ? xv[r].y : (i == 2) ? xv[r].z : xv[r].w;
          acc[r][0] = fmaf(xr, wv0, acc[r][0]);
          acc[r][1] = fmaf(xr, wv1, acc[r][1]);
          acc[r][2] = fmaf(xr, wv2, acc[r][2]);
          acc[r][3] = fmaf(xr, wv3, acc[r][3]);
        }
      }
    }
    __syncthreads();
  }
  float lamv = lam[ct];
  float la = logf(1.f / (1.f + expf(-lamv)) + 1e-8f);
  float bv = Wab[ct];
  #pragma unroll
  for (int r = 0; r < 4; r++) {
    float nk = wave_reduce_add_f32(acc[r][0] * acc[r][0]);
    float nq = wave_reduce_add_f32(acc[r][2] * acc[r][2]);
    nk = fmaxf(sqrtf(nk), 1e-12f);
    nq = fmaxf(sqrtf(nq), 1e-12f);
    float pre = acc[r][3] + bv;
    float rr_ = 1.f / (1.f + expf(-pre));
    float al  = expf(8.f * rr_ * la);
    float kn  = acc[r][0] / nk;
    float qn  = acc[r][2] / nq;
    float qw  = wave_reduce_add_f32(qn * (1.f - al) * kn);
    float* pr = proj + (size_t)(r0 + rt * 4 + r) * 256;
    pr[ct]        = kn;
    pr[64 + ct]   = acc[r][1];
    pr[128 + ct]  = qn;
    pr[192 + ct]  = al;
    if (ct == 0) qwArr[r0 + rt * 4 + r] = qw;
  }
}

// ---------------------------------------------------------------------------
// K1b: per-PHASE cross-step scalars (phase p = steps t=2p, t+1).
// Consuming phase p's prev-phase decomposition: H_{t-1} = A' H_{t-3} +
// W0p g_{t-2} + W1p g_{t-1}, with W0p = a_{t-1}*w_{t-2}, W1p = w_{t-1}.
// 17 scalars packed as 5 float4 at scArr[P*20]:
//  [0] sq00=(q_t.W0p)      sq01=(q_t.W1p)      sk00=(k_t.W0p)     sk01=(k_t.W1p)
//  [1] sy00=(q_t a_t.W0p)  sy01=(q_t a_t.W1p)  qw0=(q_t.w_t)      sq10=(q1 a0.W0p)
//  [2] sq11=(q1 a0.W1p)    sk10=(k1 a0.W0p)    sk11=(k1 a0.W1p)   sy10=(q1a1a0.W0p)
//  [3] sy11=(q1a1a0.W1p)   cqi=(q1.w_t)        cki=(k1.w_t)       cyi=(q1 a1.w_t)
//  [4] qw1=(q1.w_{t+1})    0 0 0                 (q1,a1,k1 = row t+1)
// Boundary p=0: W0p=W1p=0.
// ---------------------------------------------------------------------------
__global__ __launch_bounds__(256) void k_coef(const float* __restrict__ proj,
                                              float* __restrict__ scArr)
{
  const int P    = blockIdx.x * 4 + (threadIdx.x >> 6);   // 4096 phases total
  const int lane = threadIdx.x & 63;
  const int p    = P & (NPH - 1);
  const int t    = p * 2;
  const float* pr0 = proj + ((size_t)(P >> 10) * S_ + t) * 256;  // row t
  const float* pr1 = pr0 + 256;                                  // row t+1
  float k0 = pr0[lane], q0 = pr0[128 + lane], a0 = pr0[192 + lane];
  float k1 = pr1[lane], q1 = pr1[128 + lane], a1 = pr1[192 + lane];
  float w0 = (1.f - a0) * k0;
  float w1 = (1.f - a1) * k1;
  float W0p = 0.f, W1p = 0.f;
  if (p > 0) {
    const float* pm1 = pr0 - 256;   // row t-1
    const float* pm2 = pr0 - 512;   // row t-2
    float am1 = pm1[192 + lane], km1 = pm1[lane];
    float am2 = pm2[192 + lane], km2 = pm2[lane];
    float wm2 = (1.f - am2) * km2;
    W0p = am1 * wm2;
    W1p = (1.f - am1) * km1;
  }
  float q0a0 = q0 * a0;
  float q1a0 = q1 * a0;
  float k1a0 = k1 * a0;
  float q1a1a0 = q1a0 * a1;
  float sq00 = wave_reduce_add_f32(q0 * W0p);
  float sq01 = wave_reduce_add_f32(q0 * W1p);
  float sk00 = wave_reduce_add_f32(k0 * W0p);
  float sk01 = wave_reduce_add_f32(k0 * W1p);
  float sy00 = wave_reduce_add_f32(q0a0 * W0p);
  float sy01 = wave_reduce_add_f32(q0a0 * W1p);
  float qw0  = wave_reduce_add_f32(q0 * w0);
  float sq10 = wave_reduce_add_f32(q1a0 * W0p);
  float sq11 = wave_reduce_add_f32(q1a0 * W1p);
  float sk10 = wave_reduce_add_f32(k1a0 * W0p);
  float sk11 = wave_reduce_add_f32(k1a0 * W1p);
  float sy10 = wave_reduce_add_f32(q1a1a0 * W0p);
  float sy11 = wave_reduce_add_f32(q1a1a0 * W1p);
  float cqi  = wave_reduce_add_f32(q1 * w0);
  float cki  = wave_reduce_add_f32(k1 * w0);
  float cyi  = wave_reduce_add_f32(q1 * a1 * w0);
  float qw1  = wave_reduce_add_f32(q1 * w1);
  if (lane == 0) {
    float4* so = (float4*)(scArr + (size_t)P * 20);
    so[0] = make_float4(sq00, sq01, sk00, sk01);
    so[1] = make_float4(sy00, sy01, qw0, sq10);
    so[2] = make_float4(sq11, sk10, sk11, sy10);
    so[3] = make_float4(sy11, cqi, cki, cyi);
    so[4] = make_float4(qw1, 0.f, 0.f, 0.f);
  }
}

// ---------------------------------------------------------------------------
// K2: sequential scan, 2-step phases. 1 block/batch, 4 waves x 16 H-rows,
// lane = v-column. Per phase (steps t,t+1): ONE barrier, ONE lgkm drain,
// ONE xch-read round, 2 DPP reduces. Dots for steps t+2,t+3 computed vs
// ENTRY H (coeffs x A = a_{t+1}a_t, in-register from nxt rows), exchanged
// as float4/wave; scalar couplings to this phase's g's come from k_coef.
// 8-slot row ring in LDS; rows t..t+5 live; write rows t+6,t+7/phase.
// ---------------------------------------------------------------------------
struct Rows { float4 q[2][4], k[2][4], a[2][4]; };  // [row parity][quad]

__device__ __forceinline__ void load_rows(const float* __restrict__ inv,
                                          int sA, int sB, int w, Rows& R) {
  const float4* r0 = (const float4*)(inv + (sA << 8));
  const float4* r1 = (const float4*)(inv + (sB << 8));
  const int o = w * 4;
  #pragma unroll
  for (int i = 0; i < 4; i++) {
    R.k[0][i] = r0[o + i];       R.k[1][i] = r1[o + i];
    R.q[0][i] = r0[32 + o + i];  R.q[1][i] = r1[32 + o + i];
    R.a[0][i] = r0[48 + o + i];  R.a[1][i] = r1[48 + o + i];
  }
}

#define PHASE_DOT(J, C, HI) { \
  float A_  = CUR.a[1][J].C * CUR.a[0][J].C; \
  float c1_ = NXT.q[0][J].C * A_; \
  float c2_ = NXT.k[0][J].C * A_; \
  float c3_ = c1_ * NXT.a[0][J].C; \
  float am_ = NXT.a[0][J].C * A_; \
  float f1_ = NXT.q[1][J].C * am_; \
  float f2_ = NXT.k[1][J].C * am_; \
  float f3_ = f1_ * NXT.a[1][J].C; \
  float h_  = H[4*(J)+(HI)]; \
  D1n = fmaf(c1_, h_, D1n); D2n = fmaf(c2_, h_, D2n); D3n = fmaf(c3_, h_, D3n); \
  D1m = fmaf(f1_, h_, D1m); D2m = fmaf(f2_, h_, D2m); D3m = fmaf(f3_, h_, D3m); }

#define PHASE_HUP(J, C, HI) { \
  float a0_ = CUR.a[0][J].C, a1_ = CUR.a[1][J].C; \
  float w0_ = (1.f - a0_) * CUR.k[0][J].C; \
  float w1_ = (1.f - a1_) * CUR.k[1][J].C; \
  float tm_ = fmaf(w1_, g1, (a1_ * w0_) * g0); \
  H[4*(J)+(HI)] = fmaf(a1_ * a0_, H[4*(J)+(HI)], tm_); }

__device__ __forceinline__ void pstep(int t,
    const float4* __restrict__ sc, float4* __restrict__ scn,
    const float4* __restrict__ scb,
    float* __restrict__ inv, const float4* __restrict__ xchR,
    float4* __restrict__ xchW, float* __restrict__ yb,
    const float* __restrict__ pb, float H[16], Rows& CUR, Rows& NXT,
    float& d3c0, float& d3c1, float& g0p, float& g1p,
    float& pfE, float& pfO, int w, int lane, int tid, float qwSel)
{
  // prefetch next phase's scalars (uniform -> s_load; 1-phase budget)
  {
    const float4* sp = scb + (size_t)min((t >> 1) + 1, NPH - 1) * 5;
    scn[0] = sp[0]; scn[1] = sp[1]; scn[2] = sp[2]; scn[3] = sp[3]; scn[4] = sp[4];
  }
  // LDS reads issued early: v of cur rows, next-phase rows (slots t+2,t+3)
  float v0 = inv[((t & 7) << 8) + 64 + lane];
  float v1 = inv[(((t + 1) & 7) << 8) + 64 + lane];
  load_rows(inv, (t + 2) & 7, (t + 3) & 7, w, NXT);
  // exchange read (written last phase, fenced by its barrier)
  float4 x0 = xchR[lane], x1 = xchR[64 + lane], x2 = xchR[128 + lane], x3 = xchR[192 + lane];
  float D1  = (x0.x + x1.x) + (x2.x + x3.x);
  float D2  = (x0.y + x1.y) + (x2.y + x3.y);
  float D1b = (x0.z + x1.z) + (x2.z + x3.z);
  float D2b = (x0.w + x1.w) + (x2.w + x3.w);
  // --- step t ---
  float pred0 = fmaf(sc[0].x, g0p, fmaf(sc[0].y, g1p, D1));
  float kh0   = fmaf(sc[0].z, g0p, fmaf(sc[0].w, g1p, D2));
  float d0 = v0 - pred0;
  float e0 = wave_reduce_add_f32(d0 * d0);
  float sg0 = __builtin_amdgcn_rcpf(1.f + __builtin_amdgcn_exp2f(e0 * -1.4426936f));
  float g0 = sg0 * (v0 - kh0);
  yb[(size_t)t * 256 + tid] = d3c0 + qwSel * fmaf(sc[1].x, g0p, fmaf(sc[1].y, g1p, sc[1].z * g0));
  // --- step t+1 ---
  float pred1 = fmaf(sc[3].y, g0, fmaf(sc[1].w, g0p, fmaf(sc[2].x, g1p, D1b)));
  float kh1   = fmaf(sc[3].z, g0, fmaf(sc[2].y, g0p, fmaf(sc[2].z, g1p, D2b)));
  float d1 = v1 - pred1;
  float e1 = wave_reduce_add_f32(d1 * d1);
  float sg1 = __builtin_amdgcn_rcpf(1.f + __builtin_amdgcn_exp2f(e1 * -1.4426936f));
  float g1 = sg1 * (v1 - kh1);
  yb[(size_t)(t + 1) * 256 + tid] =
      d3c1 + qwSel * fmaf(sc[2].w, g0p, fmaf(sc[3].x, g1p, fmaf(sc[3].w, g0, sc[4].x * g1)));
  // --- dots for steps t+2,t+3 vs ENTRY H (independent of g0,g1) ---
  float D1n = 0.f, D2n = 0.f, D3n = 0.f, D1m = 0.f, D2m = 0.f, D3m = 0.f;
  #pragma unroll
  for (int j = 0; j < 4; j++) {
    PHASE_DOT(j, x, 0); PHASE_DOT(j, y, 1); PHASE_DOT(j, z, 2); PHASE_DOT(j, w, 3);
  }
  d3c0 = D3n;
  d3c1 = D3m;
  xchW[(w << 6) + lane] = make_float4(D1n, D2n, D1m, D2m);
  // --- H update: H = (a1 a0) H + (a1 w0) g0 + w1 g1 ---
  #pragma unroll
  for (int j = 0; j < 4; j++) {
    PHASE_HUP(j, x, 0); PHASE_HUP(j, y, 1); PHASE_HUP(j, z, 2); PHASE_HUP(j, w, 3);
  }
  // --- staging: write rows t+6,t+7 (prefetched last phase); prefetch t+8,t+9 ---
  inv[(((t + 6) & 7) << 8) + tid] = pfE;
  inv[(((t + 7) & 7) << 8) + tid] = pfO;
  pfE = pb[(size_t)min(t + 8, S_ - 1) * 256 + tid];
  pfO = pb[(size_t)min(t + 9, S_ - 1) * 256 + tid];
  asm volatile("s_waitcnt lgkmcnt(0)\n\ts_barrier" ::: "memory");
  g0p = g0; g1p = g1;
}

__global__ __launch_bounds__(256, 1) void k_scan(const float* __restrict__ proj,
    const float* __restrict__ scArr, float* __restrict__ ypart)
{
  __shared__ __align__(16) float inv[8 * 256];     // 8-slot row ring
  __shared__ __align__(16) float4 xch[2][256];     // ping-pong exchange (float4/wave)
  const int b = blockIdx.x, tid = threadIdx.x;
  const int w = tid >> 6, lane = tid & 63;
  const float* pb = proj + (size_t)b * S_ * 256;
  const float4* scb = (const float4*)scArr + (size_t)b * NPH * 5;
  float* yb = ypart + (size_t)b * S_ * 256;
  float H[16];
  #pragma unroll
  for (int j = 0; j < 16; j++) H[j] = 0.f;
  float d3c0 = 0.f, d3c1 = 0.f, g0p = 0.f, g1p = 0.f;
  xch[0][tid] = make_float4(0.f, 0.f, 0.f, 0.f);   // dots for steps 0,1 vs H_{-1}=0
  #pragma unroll
  for (int i = 0; i < 6; i++) inv[i * 256 + tid] = pb[i * 256 + tid];
  float pfE = pb[6 * 256 + tid];
  float pfO = pb[7 * 256 + tid];
  float4 scA[5], scB[5];
  { const float4* sp = scb; scA[0]=sp[0]; scA[1]=sp[1]; scA[2]=sp[2]; scA[3]=sp[3]; scA[4]=sp[4]; }
  __syncthreads();
  Rows RA, RB;
  load_rows(inv, 0, 1, w, RA);   // rows 0,1 (CUR role: a,k used)
  const float qwSel = (w == 0) ? 1.f : 0.f;
  for (int t = 0; t < S_; t += 4) {
    pstep(t,     scA, scB, scb, inv, xch[0], xch[1], yb, pb, H, RA, RB,
          d3c0, d3c1, g0p, g1p, pfE, pfO, w, lane, tid, qwSel);
    pstep(t + 2, scB, scA, scb, inv, xch[1], xch[0], yb, pb, H, RB, RA,
          d3c0, d3c1, g0p, g1p, pfE, pfO, w, lane, tid, qwSel);
  }
}

// ---------------------------------------------------------------------------
// Wo transpose (2048x64 -> 64x2048).
// ---------------------------------------------------------------------------
__global__ __launch_bounds__(256) void k_trans(const float* __restrict__ Wo,
                                               float* __restrict__ WoT) {
  int i = blockIdx.x * 256 + threadIdx.x;
  int d = i >> 11;
  int c = i & 2047;
  WoT[i] = Wo[(size_t)c * 64 + d];
}

// ---------------------------------------------------------------------------
// K3: sum y-partials, RMS-norm over 64, * norm_w, then yn @ Wo^T. (unchanged)
// ---------------------------------------------------------------------------
__global__ __launch_bounds__(256) void k_out(const float* __restrict__ ypart,
    const float* __restrict__ norm_w, const float* __restrict__ WoT,
    float* __restrict__ out)
{
  __shared__ __align__(16) float yn[16 * 64];
  const int tid = threadIdx.x;
  const int r0  = blockIdx.x * 16;
  const int c0  = blockIdx.y * 512;
  {
    const int r = tid >> 4;
    const int d = (tid & 15) * 4;
    const float* yp = ypart + (size_t)(r0 + r) * 256;
    float4 y0 = *(const float4*)(yp + d);
    float4 y1 = *(const float4*)(yp + 64 + d);
    float4 y2 = *(const float4*)(yp + 128 + d);
    float4 y3 = *(const float4*)(yp + 192 + d);
    float yx = y0.x + y1.x + y2.x + y3.x;
    float yy = y0.y + y1.y + y2.y + y3.y;
    float yz = y0.z + y1.z + y2.z + y3.z;
    float yw = y0.w + y1.w + y2.w + y3.w;
    float sq = yx * yx + yy * yy + yz * yz + yw * yw;
    sq += __shfl_xor(sq, 1, 64);
    sq += __shfl_xor(sq, 2, 64);
    sq += __shfl_xor(sq, 4, 64);
    sq += __shfl_xor(sq, 8, 64);
    float rms = rsqrtf(sq * (1.f / 64.f) + 1e-6f);
    float4 nw = *(const float4*)(norm_w + d);
    yn[r * 64 + d + 0] = yx * rms * nw.x;
    yn[r * 64 + d + 1] = yy * rms * nw.y;
    yn[r * 64 + d + 2] = yz * rms * nw.z;
    yn[r * 64 + d + 3] = yw * rms * nw.w;
  }
  __syncthreads();
  const int ctq = tid & 127;
  const int rt  = tid >> 7;
  float acc[8][4];
  #pragma unroll
  for (int r = 0; r < 8; r++) { acc[r][0] = 0.f; acc[r][1] = 0.f; acc[r][2] = 0.f; acc[r][3] = 0.f; }
  #pragma unroll 8
  for (int d = 0; d < 64; d++) {
    float4 wv = *(const float4*)(WoT + (size_t)d * 2048 + c0 + ctq * 4);
    #pragma unroll
    for (int r = 0; r < 8; r++) {
      float yv = yn[(rt * 8 + r) * 64 + d];
      acc[r][0] = fmaf(yv, wv.x, acc[r][0]);
      acc[r][1] = fmaf(yv, wv.y, acc[r][1]);
      acc[r][2] = fmaf(yv, wv.z, acc[r][2]);
      acc[r][3] = fmaf(yv, wv.w, acc[r][3]);
    }
  }
  #pragma unroll
  for (int r = 0; r < 8; r++) {
    float4 o; o.x = acc[r][0]; o.y = acc[r][1]; o.z = acc[r][2]; o.w = acc[r][3];
    *(float4*)(out + (size_t)(r0 + rt * 8 + r) * 2048 + c0 + ctq * 4) = o;
  }
}

extern "C" void kernel_launch(void* const* d_in, const int* in_sizes, int n_in,
                              void* d_out, int out_size, void* d_ws, size_t ws_size,
                              hipStream_t stream) {
  const float* x   = (const float*)d_in[0];
  const float* Wk  = (const float*)d_in[1];
  const float* Wv  = (const float*)d_in[2];
  const float* Wq  = (const float*)d_in[3];
  const float* Wa  = (const float*)d_in[4];
  const float* Wab = (const float*)d_in[5];
  const float* lam = (const float*)d_in[6];
  const float* nw  = (const float*)d_in[7];
  const float* Wo  = (const float*)d_in[8];
  float* out = (float*)d_out;

  float* wsf   = (float*)d_ws;
  float* proj  = wsf;                 // 4*2048*256 = 2,097,152 floats
  float* ypart = wsf + 2097152;       // 4*2048*256 = 2,097,152 floats
  float* WoT   = wsf + 4194304;       // 64*2048    =   131,072 floats
  float* qwArr = wsf + 4325376;       // 4*2048     =     8,192 floats
  float* scArr = wsf + 4333568;       // 4096*20    =    81,920 floats (17.66 MB total)

  k_trans<<<dim3(512), dim3(256), 0, stream>>>(Wo, WoT);
  k_proj <<<dim3(512), dim3(256), 0, stream>>>(x, Wk, Wv, Wq, Wa, Wab, lam, proj, qwArr);
  k_coef <<<dim3(1024), dim3(256), 0, stream>>>(proj, scArr);
  k_scan <<<dim3(4),   dim3(256), 0, stream>>>(proj, scArr, ypart);
  k_out  <<<dim3(512, 4), dim3(256), 0, stream>>>(ypart, nw, WoT, out);
}